// Round 7
// baseline (396.740 us; speedup 1.0000x reference)
//
#include <hip/hip_runtime.h>

#define NIT 21
#define SMIN 1e-33f

// Round-7 bisect: 1 wave per 128x128 matrix, NO inline asm, NO DPP, NO LDS,
// NO barriers. Only cross-lane primitive: __shfl_xor (validated r2/r4).
// Lane (lr=lane>>3, lc=lane&7) owns rows lr*16..+15, cols {g*32+lc*4+k}.
// E[16][16] scalars (~256 regs; compiler may use AGPRs). Linear-space
// Sinkhorn with lazy a_i/b_j reciprocal factors (numerics validated r2/r4).
__global__ __launch_bounds__(64, 1) void sinkhorn_kernel(const float* __restrict__ in,
                                                         float* __restrict__ out) {
    const int lane = threadIdx.x;
    const int lr = lane >> 3;
    const int lc = lane & 7;
    const size_t base = (size_t)blockIdx.x * (128 * 128);
    const float* __restrict__ src = in  + base + ((size_t)lr << 11) + (lc << 2);
    float*       __restrict__ dst = out + base + ((size_t)lr << 11) + (lc << 2);

    const float S = 36.067376022224085f;  // (1/0.04) * log2(e)

    float E[16][16];
#pragma unroll
    for (int r = 0; r < 16; ++r) {
#pragma unroll
        for (int g = 0; g < 4; ++g) {
            float4 f = *(const float4*)(src + (r << 7) + (g << 5));
            E[r][4 * g + 0] = f.x;
            E[r][4 * g + 1] = f.y;
            E[r][4 * g + 2] = f.z;
            E[r][4 * g + 3] = f.w;
        }
    }

    float a[16], b[16];

    // ---- init: row max over 128 cols, E = 2^((x-m)*S), a = rcp(rowsum) ----
#pragma unroll
    for (int r = 0; r < 16; ++r) {
        float m = E[r][0];
#pragma unroll
        for (int c = 1; c < 16; ++c) m = fmaxf(m, E[r][c]);
        m = fmaxf(m, __shfl_xor(m, 1));
        m = fmaxf(m, __shfl_xor(m, 2));
        m = fmaxf(m, __shfl_xor(m, 4));
        const float nms = -m * S;
        float s0 = 0.f, s1 = 0.f;
#pragma unroll
        for (int c = 0; c < 16; ++c) {
            float e = __builtin_amdgcn_exp2f(fmaf(E[r][c], S, nms));
            E[r][c] = e;
            if (c & 1) s1 += e; else s0 += e;
        }
        float s = s0 + s1;
        s += __shfl_xor(s, 1);
        s += __shfl_xor(s, 2);
        s += __shfl_xor(s, 4);
        a[r] = __builtin_amdgcn_rcpf(fmaxf(s, SMIN));   // s in [1,128]
    }

#pragma unroll 1
    for (int it = 0; it < NIT; ++it) {
        // ---- col phase: b_c = rcp( sum_rows E * a ) ----
        float sc[16];
#pragma unroll
        for (int c = 0; c < 16; ++c) sc[c] = 0.f;
#pragma unroll
        for (int r = 0; r < 16; ++r) {
            const float ar = a[r];
#pragma unroll
            for (int c = 0; c < 16; ++c) sc[c] = fmaf(E[r][c], ar, sc[c]);
        }
#pragma unroll
        for (int c = 0; c < 16; ++c) {
            float v = sc[c];
            v += __shfl_xor(v, 8);
            v += __shfl_xor(v, 16);
            v += __shfl_xor(v, 32);
            b[c] = __builtin_amdgcn_rcpf(fmaxf(v, SMIN));
        }
        // ---- row phase: a_r = rcp( sum_cols E * b )  (skipped after last col) ----
        if (it < NIT - 1) {
#pragma unroll
            for (int r = 0; r < 16; ++r) {
                float s0 = 0.f, s1 = 0.f;
#pragma unroll
                for (int c = 0; c < 16; ++c) {
                    if (c & 1) s1 = fmaf(E[r][c], b[c], s1);
                    else       s0 = fmaf(E[r][c], b[c], s0);
                }
                float s = s0 + s1;
                s += __shfl_xor(s, 1);
                s += __shfl_xor(s, 2);
                s += __shfl_xor(s, 4);
                a[r] = __builtin_amdgcn_rcpf(fmaxf(s, SMIN));
            }
        }
    }

    // ---- epilogue: out = E * a_r * b_c ----
#pragma unroll
    for (int r = 0; r < 16; ++r) {
        const float ar = a[r];
#pragma unroll
        for (int g = 0; g < 4; ++g) {
            float4 o;
            o.x = E[r][4 * g + 0] * ar * b[4 * g + 0];
            o.y = E[r][4 * g + 1] * ar * b[4 * g + 1];
            o.z = E[r][4 * g + 2] * ar * b[4 * g + 2];
            o.w = E[r][4 * g + 3] * ar * b[4 * g + 3];
            *(float4*)(dst + (r << 7) + (g << 5)) = o;
        }
    }
}

extern "C" void kernel_launch(void* const* d_in, const int* in_sizes, int n_in,
                              void* d_out, int out_size, void* d_ws, size_t ws_size,
                              hipStream_t stream) {
    (void)n_in; (void)d_ws; (void)ws_size; (void)out_size;
    const float* in  = (const float*)d_in[0];
    float*       out = (float*)d_out;
    const int n_mat = in_sizes[0] / (128 * 128);  // 4096
    sinkhorn_kernel<<<dim3(n_mat), dim3(64), 0, stream>>>(in, out);
}